// Round 4
// baseline (488.866 us; speedup 1.0000x reference)
//
#include <hip/hip_runtime.h>
#include <hip/hip_bf16.h>
#include <cstdint>

typedef __bf16 bf16;
typedef bf16 bf16x8 __attribute__((ext_vector_type(8)));
typedef float f32x4 __attribute__((ext_vector_type(4)));

#define MFMA16(a, b, c) __builtin_amdgcn_mfma_f32_16x16x32_bf16(a, b, c, 0, 0, 0)

// load 8 consecutive elements as bf16x8 (converting if fp32)
__device__ inline bf16x8 ld8(const bf16* p) { return *(const bf16x8*)p; }
__device__ inline bf16x8 ld8(const float* p) {
  f32x4 a = *(const f32x4*)p;
  f32x4 b = *(const f32x4*)(p + 4);
  bf16x8 r;
#pragma unroll
  for (int i = 0; i < 4; ++i) { r[i] = (bf16)a[i]; r[i + 4] = (bf16)b[i]; }
  return r;
}
__device__ inline void stC(bf16* C, size_t idx, float v) { C[idx] = (bf16)v; }
__device__ inline void stC(float* C, size_t idx, float v) { C[idx] = v; }

// ---------------- GEMM: C[M,N] = A[M,K] @ B[K,N], fp32 acc, bf16 MFMA ----------
// A: [M,K] (fp32 or bf16); B: [K,N] native layout (transposed into LDS); C: fp32 or bf16.
// 128x128 tile, BK=32, 256 threads = 4 waves (2x2), each wave 64x64 (4x4 frags)
template <typename TA, typename TB, typename TC>
__global__ __launch_bounds__(256) void gemm_bn(const TA* __restrict__ A,
                                               const TB* __restrict__ Bm,
                                               TC* __restrict__ C, int M, int N, int K) {
  const int LDS = 40;  // padded stride (elements); 80B rows, 16B-aligned
  __shared__ bf16 As[128 * 40];  // As[m][k]
  __shared__ bf16 Bs[128 * 40];  // Bs[n][k]  (B transposed)
  int tid = threadIdx.x;
  int wave = tid >> 6, lane = tid & 63;
  int la = lane & 15, quad = lane >> 4;
  int wr = (wave >> 1) * 64, wc = (wave & 1) * 64;
  const TA* Ab = A + (size_t)blockIdx.x * 128 * K;
  int n0 = blockIdx.y * 128;

  f32x4 zero = {0.f, 0.f, 0.f, 0.f};
  f32x4 acc[4][4];
#pragma unroll
  for (int i = 0; i < 4; ++i)
#pragma unroll
    for (int j = 0; j < 4; ++j) acc[i][j] = zero;

  for (int k0 = 0; k0 < K; k0 += 32) {
    // stage A: 128 rows x 32 k
#pragma unroll
    for (int p = 0; p < 2; ++p) {
      int li = (tid + p * 256) * 8;
      int r = li >> 5, c = li & 31;
      *(bf16x8*)&As[r * LDS + c] = ld8(&Ab[(size_t)r * K + k0 + c]);
    }
    // stage B: 32 k-rows x 128 n, transposed into Bs[n][k]
#pragma unroll
    for (int p = 0; p < 2; ++p) {
      int li = (tid + p * 256) * 8;
      int kr = li >> 7, nc = li & 127;
      bf16x8 v = ld8(&Bm[(size_t)(k0 + kr) * N + n0 + nc]);
#pragma unroll
      for (int j = 0; j < 8; ++j) Bs[(nc + j) * LDS + kr] = v[j];
    }
    __syncthreads();
    bf16x8 af[4], bfr[4];
#pragma unroll
    for (int i = 0; i < 4; ++i)
      af[i] = *(const bf16x8*)&As[(wr + i * 16 + la) * LDS + quad * 8];
#pragma unroll
    for (int j = 0; j < 4; ++j)
      bfr[j] = *(const bf16x8*)&Bs[(wc + j * 16 + la) * LDS + quad * 8];
#pragma unroll
    for (int i = 0; i < 4; ++i)
#pragma unroll
      for (int j = 0; j < 4; ++j) acc[i][j] = MFMA16(af[i], bfr[j], acc[i][j]);
    __syncthreads();
  }
  // epilogue: C/D layout col = lane&15, row = quad*4 + r  [m89-verified]
#pragma unroll
  for (int i = 0; i < 4; ++i) {
#pragma unroll
    for (int j = 0; j < 4; ++j) {
      int col = n0 + wc + j * 16 + la;
#pragma unroll
      for (int r = 0; r < 4; ++r) {
        int row = blockIdx.x * 128 + wr + i * 16 + quad * 4 + r;
        stC(C, (size_t)row * N + col, acc[i][j][r]);
      }
    }
  }
}

// ---------------- flash attention, causal, HD=64, bf16 in/out ----------------
// grid: (S/64, B*H). block: 256 = 4 waves; wave w owns q rows q0+w*16 .. +15.
// O may alias Q (Q rows preloaded to regs; block-private rows).
__global__ __launch_bounds__(256) void flash_attn(const bf16* __restrict__ Q,
                                                  const bf16* __restrict__ K,
                                                  const bf16* __restrict__ V,
                                                  bf16* __restrict__ O) {
  constexpr int D = 1024, S = 2048, H = 16;
  const int LDK = 72;  // padded (144B rows, 16B-aligned)
  const float MASK = -3.0e4f;  // finite sentinel; no +/-inf anywhere
  __shared__ bf16 Ks[64 * 72];      // Ks[key][hd]
  __shared__ bf16 Vt[64 * 72];      // Vt[hd][key]
  __shared__ bf16 Ps[4][16 * 72];   // per-wave P tile [q][key]

  int qt = blockIdx.x, bh = blockIdx.y;
  int b = bh / H, h = bh % H;
  int tid = threadIdx.x, wave = tid >> 6, lane = tid & 63;
  int la = lane & 15, quad = lane >> 4;
  int q0 = qt * 64;
  const size_t base = (size_t)b * S * D + (size_t)h * 64;
  const bf16* Qb = Q + base;
  const bf16* Kb = K + base;
  const bf16* Vb = V + base;

  // preload Q A-frags: A[m=lane&15][k=quad*8+j] per 32-wide k chunk
  bf16x8 aq[2];
  int qrow = q0 + wave * 16 + la;
#pragma unroll
  for (int kc = 0; kc < 2; ++kc)
    aq[kc] = *(const bf16x8*)&Qb[(size_t)qrow * D + kc * 32 + quad * 8];

  f32x4 zero = {0.f, 0.f, 0.f, 0.f};
  f32x4 o[4];
  float m_r[4], l_r[4];
#pragma unroll
  for (int r = 0; r < 4; ++r) { m_r[r] = MASK; l_r[r] = 0.f; }
#pragma unroll
  for (int nt = 0; nt < 4; ++nt) o[nt] = zero;

  int ntiles = qt + 1;  // causal
  for (int t = 0; t < ntiles; ++t) {
    int kb = t * 64;
#pragma unroll
    for (int p = 0; p < 2; ++p) {
      int li = (tid + p * 256) * 8;
      int r = li >> 6, c = li & 63;
      *(bf16x8*)&Ks[r * LDK + c] = *(const bf16x8*)&Kb[(size_t)(kb + r) * D + c];
      bf16x8 v = *(const bf16x8*)&Vb[(size_t)(kb + r) * D + c];
#pragma unroll
      for (int j = 0; j < 8; ++j) Vt[(c + j) * LDK + r] = v[j];
    }
    __syncthreads();

    // S = Q @ K^T
    f32x4 s[4];
#pragma unroll
    for (int nt = 0; nt < 4; ++nt) {
      bf16x8 bk0 = *(const bf16x8*)&Ks[(nt * 16 + la) * LDK + quad * 8];
      bf16x8 bk1 = *(const bf16x8*)&Ks[(nt * 16 + la) * LDK + 32 + quad * 8];
      f32x4 z = zero;
      z = MFMA16(aq[0], bk0, z);
      z = MFMA16(aq[1], bk1, z);
      s[nt] = z;
    }

    // online softmax per q-row (rows at quad*4+r; cols at lane&15)
#pragma unroll
    for (int r = 0; r < 4; ++r) {
      int qa = q0 + wave * 16 + quad * 4 + r;
      float mx = MASK;
#pragma unroll
      for (int nt = 0; nt < 4; ++nt) {
        int ka = kb + nt * 16 + la;
        float sv = s[nt][r] * 0.125f;  // 1/sqrt(64)
        sv = (ka > qa) ? MASK : sv;
        s[nt][r] = sv;
        mx = fmaxf(mx, sv);
      }
#pragma unroll
      for (int off = 1; off < 16; off <<= 1) mx = fmaxf(mx, __shfl_xor(mx, off, 64));
      float mnew = fmaxf(m_r[r], mx);
      float alpha = __expf(m_r[r] - mnew);
      float rs = 0.f;
#pragma unroll
      for (int nt = 0; nt < 4; ++nt) {
        float p = __expf(s[nt][r] - mnew);
        s[nt][r] = p;
        rs += p;
      }
#pragma unroll
      for (int off = 1; off < 16; off <<= 1) rs += __shfl_xor(rs, off, 64);
      l_r[r] = l_r[r] * alpha + rs;
      m_r[r] = mnew;
#pragma unroll
      for (int nt = 0; nt < 4; ++nt) o[nt][r] *= alpha;
#pragma unroll
      for (int nt = 0; nt < 4; ++nt)
        Ps[wave][(quad * 4 + r) * LDK + nt * 16 + la] = (bf16)s[nt][r];
    }
    __syncthreads();  // P spill visible before PV reads

    // O += P @ V
#pragma unroll
    for (int kc = 0; kc < 2; ++kc) {
      bf16x8 ap = *(const bf16x8*)&Ps[wave][la * LDK + kc * 32 + quad * 8];
#pragma unroll
      for (int nt = 0; nt < 4; ++nt) {
        bf16x8 bv = *(const bf16x8*)&Vt[(nt * 16 + la) * LDK + kc * 32 + quad * 8];
        o[nt] = MFMA16(ap, bv, o[nt]);
      }
    }
    __syncthreads();
  }

  // epilogue: normalize and store
#pragma unroll
  for (int nt = 0; nt < 4; ++nt) {
    int hd = nt * 16 + la;
#pragma unroll
    for (int r = 0; r < 4; ++r) {
      int row = q0 + wave * 16 + quad * 4 + r;
      float inv = (l_r[r] > 1e-30f) ? 1.0f / l_r[r] : 0.0f;
      O[base + (size_t)row * D + hd] = (bf16)(o[nt][r] * inv);
    }
  }
}

extern "C" void kernel_launch(void* const* d_in, const int* in_sizes, int n_in,
                              void* d_out, int out_size, void* d_ws, size_t ws_size,
                              hipStream_t stream) {
  constexpr int B = 2, S = 2048, D = 1024;
  constexpr int M = B * S;                  // 4096
  constexpr size_t XN = (size_t)M * D;      // 4M elements

  // Inputs/outputs are fp32 per the reference (jnp.float32 everywhere).
  const float* x  = (const float*)d_in[0];
  const float* Wq = (const float*)d_in[1];
  const float* Wk = (const float*)d_in[2];
  const float* Wv = (const float*)d_in[3];
  const float* Wo = (const float*)d_in[4];
  float* out = (float*)d_out;

  // bf16 intermediates: Qb (O aliases it) + Vb in ws (16 MB); Kb scratched in
  // d_out (8 MB of its 16 MB) — flash consumes K before the final gemm writes out.
  if (ws_size < 2 * XN * sizeof(bf16)) return;  // diagnostic: leaves out == 0
  bf16* Qb = (bf16*)d_ws;
  bf16* Vb = Qb + XN;
  bf16* Kb = (bf16*)d_out;

  dim3 ggrid(M / 128, D / 128);  // (32, 8)
  gemm_bn<float, float, bf16><<<ggrid, 256, 0, stream>>>(x, Wq, Qb, M, D, D);
  gemm_bn<float, float, bf16><<<ggrid, 256, 0, stream>>>(x, Wk, Kb, M, D, D);
  gemm_bn<float, float, bf16><<<ggrid, 256, 0, stream>>>(x, Wv, Vb, M, D, D);

  flash_attn<<<dim3(S / 64, B * 16), 256, 0, stream>>>(Qb, Kb, Vb, /*O=*/Qb);

  gemm_bn<bf16, float, float><<<ggrid, 256, 0, stream>>>(Qb, Wo, out, M, D, D);
}

// Round 5
// 277.019 us; speedup vs baseline: 1.7647x; 1.7647x over previous
//
#include <hip/hip_runtime.h>
#include <hip/hip_bf16.h>
#include <cstdint>

typedef __bf16 bf16;
typedef bf16 bf16x8 __attribute__((ext_vector_type(8)));
typedef float f32x4 __attribute__((ext_vector_type(4)));

#define MFMA16(a, b, c) __builtin_amdgcn_mfma_f32_16x16x32_bf16(a, b, c, 0, 0, 0)

__device__ inline bf16x8 ld8(const bf16* p) { return *(const bf16x8*)p; }
__device__ inline bf16x8 ld8(const float* p) {
  f32x4 a = *(const f32x4*)p;
  f32x4 b = *(const f32x4*)(p + 4);
  bf16x8 r;
#pragma unroll
  for (int i = 0; i < 4; ++i) { r[i] = (bf16)a[i]; r[i + 4] = (bf16)b[i]; }
  return r;
}
__device__ inline void stC(bf16* C, size_t i, float v) { C[i] = (bf16)v; }
__device__ inline void stC(float* C, size_t i, float v) { C[i] = v; }

// ---- prep: transpose-convert 4 weights fp32 [K][N] -> bf16 [N][K] (z selects W) ----
__global__ __launch_bounds__(256) void prep_wt(const float* __restrict__ W0,
                                               const float* __restrict__ W1,
                                               const float* __restrict__ W2,
                                               const float* __restrict__ W3,
                                               bf16* __restrict__ Wt, int n) {
  const float* Ws[4] = {W0, W1, W2, W3};
  const float* W = Ws[blockIdx.z];
  bf16* out = Wt + (size_t)blockIdx.z * n * n;
  __shared__ bf16 t[32][33];
  int bx = blockIdx.x * 32, by = blockIdx.y * 32;  // bx: n-tile, by: k-tile
  int tx = threadIdx.x & 31, ty = threadIdx.x >> 5;
#pragma unroll
  for (int i = 0; i < 32; i += 8)
    t[ty + i][tx] = (bf16)W[(size_t)(by + ty + i) * n + bx + tx];
  __syncthreads();
#pragma unroll
  for (int i = 0; i < 32; i += 8)
    out[(size_t)(bx + ty + i) * n + by + tx] = t[tx][ty + i];
}

// ---- transpose V bf16 [4096][1024]=[b][s][h*64+hd] -> Vt [bh][hd][2048] ----
__global__ __launch_bounds__(256) void vtrans(const bf16* __restrict__ V, bf16* __restrict__ Vt) {
  constexpr int Sn = 2048, Dn = 1024;
  __shared__ bf16 t[32][33];
  int s0 = blockIdx.x * 32, hd0 = blockIdx.y * 32, bh = blockIdx.z;
  int b = bh >> 4, h = bh & 15;
  int tx = threadIdx.x & 31, ty = threadIdx.x >> 5;
#pragma unroll
  for (int i = 0; i < 32; i += 8)
    t[ty + i][tx] = V[(size_t)(b * Sn + s0 + ty + i) * Dn + h * 64 + hd0 + tx];
  __syncthreads();
#pragma unroll
  for (int i = 0; i < 32; i += 8)
    Vt[(size_t)bh * 64 * Sn + (size_t)(hd0 + ty + i) * Sn + s0 + tx] = t[tx][ty + i];
}

// ---- GEMM C[M,N] = A[M,K] @ B, fp32 acc, bf16 MFMA; 3 outputs via blockIdx.y ----
// BT=true: B = bf16 [N][K] (vector-staged). BT=false: B = fp32 [K][N], in-LDS
// transpose with XOR-swizzled layout to break the 8-lane same-bank pattern.
template <typename TA, typename TC, bool BT>
__global__ __launch_bounds__(256) void gemm3(const TA* __restrict__ A,
                                             const void* __restrict__ B0p,
                                             const void* __restrict__ B1p,
                                             const void* __restrict__ B2p,
                                             TC* __restrict__ C0, TC* __restrict__ C1,
                                             TC* __restrict__ C2, int M, int N, int K, int nblk) {
  constexpr int LDA = 40;
  constexpr int LDB = BT ? 40 : 32;
  __shared__ bf16 As[128 * LDA];
  __shared__ bf16 Bs[128 * LDB];
  int tid = threadIdx.x, wave = tid >> 6, lane = tid & 63;
  int la = lane & 15, quad = lane >> 4;
  int wr = (wave >> 1) * 64, wc = (wave & 1) * 64;
  int by = blockIdx.y;
  int sel = by / nblk;
  int n0 = (by - sel * nblk) * 128;
  const void* Bp = sel == 0 ? B0p : (sel == 1 ? B1p : B2p);
  TC* C = sel == 0 ? C0 : (sel == 1 ? C1 : C2);
  const TA* Ab = A + (size_t)blockIdx.x * 128 * K;

  f32x4 zero = {0.f, 0.f, 0.f, 0.f};
  f32x4 acc[4][4];
#pragma unroll
  for (int i = 0; i < 4; ++i)
#pragma unroll
    for (int j = 0; j < 4; ++j) acc[i][j] = zero;

  for (int k0 = 0; k0 < K; k0 += 32) {
#pragma unroll
    for (int p = 0; p < 2; ++p) {
      int li = (tid + p * 256) * 8;
      int r = li >> 5, c = li & 31;
      *(bf16x8*)&As[r * LDA + c] = ld8(&Ab[(size_t)r * K + k0 + c]);
    }
    if constexpr (BT) {
      const bf16* Bt = (const bf16*)Bp;
#pragma unroll
      for (int p = 0; p < 2; ++p) {
        int li = (tid + p * 256) * 8;
        int r = li >> 5, c = li & 31;
        *(bf16x8*)&Bs[r * LDB + c] = ld8(&Bt[(size_t)(n0 + r) * K + k0 + c]);
      }
    } else {
      const float* Bm = (const float*)Bp;
#pragma unroll
      for (int p = 0; p < 2; ++p) {
        int li = (tid + p * 256) * 8;
        int kr = li >> 7, nc = li & 127;
        bf16x8 v = ld8(&Bm[(size_t)(k0 + kr) * N + n0 + nc]);
        int kx = kr ^ (((nc >> 3) & 3) << 3);  // swizzle: spreads same-k lane group
#pragma unroll
        for (int j = 0; j < 8; ++j) Bs[(nc + j) * 32 + kx] = v[j];
      }
    }
    __syncthreads();
    bf16x8 af[4], bfr[4];
#pragma unroll
    for (int i = 0; i < 4; ++i)
      af[i] = *(const bf16x8*)&As[(wr + i * 16 + la) * LDA + quad * 8];
#pragma unroll
    for (int j = 0; j < 4; ++j) {
      int nr = wc + j * 16 + la;
      if constexpr (BT)
        bfr[j] = *(const bf16x8*)&Bs[nr * LDB + quad * 8];
      else
        bfr[j] = *(const bf16x8*)&Bs[nr * 32 + ((quad * 8) ^ (((nr >> 3) & 3) << 3))];
    }
#pragma unroll
    for (int i = 0; i < 4; ++i)
#pragma unroll
      for (int j = 0; j < 4; ++j) acc[i][j] = MFMA16(af[i], bfr[j], acc[i][j]);
    __syncthreads();
  }
#pragma unroll
  for (int i = 0; i < 4; ++i) {
#pragma unroll
    for (int j = 0; j < 4; ++j) {
      int col = n0 + wc + j * 16 + la;
#pragma unroll
      for (int r = 0; r < 4; ++r) {
        int row = blockIdx.x * 128 + wr + i * 16 + quad * 4 + r;
        stC(C, (size_t)row * N + col, acc[i][j][r]);
      }
    }
  }
}

// ---- flash attention, causal, HD=64; V pre-transposed globally ----
// grid (32, 32); qt reversed so longest blocks dispatch first. exp2 domain.
__global__ __launch_bounds__(256) void flash_attn(const bf16* __restrict__ Q,
                                                  const bf16* __restrict__ Kg,
                                                  const bf16* __restrict__ Vtg,
                                                  bf16* __restrict__ O) {
  constexpr int D = 1024, S = 2048;
  const int LDK = 72;
  const float MASK = -3.0e4f;
  const float SCL2 = 0.18033688011112042f;  // log2(e) / sqrt(64)
  __shared__ bf16 Ks[64 * 72];     // [key][hd]
  __shared__ bf16 Vs[64 * 72];     // [hd][key]  (from global V^T, vector-staged)
  __shared__ bf16 Ps[4][16 * 72];  // per-wave P [q][key]

  int qt = (S / 64 - 1) - blockIdx.x;
  int bh = blockIdx.y;
  int b = bh >> 4, h = bh & 15;
  int tid = threadIdx.x, wave = tid >> 6, lane = tid & 63;
  int la = lane & 15, quad = lane >> 4;
  int q0 = qt * 64;
  const size_t base = (size_t)b * S * D + (size_t)h * 64;
  const bf16* Qb = Q + base;
  const bf16* Kb = Kg + base;
  const bf16* Vb = Vtg + (size_t)bh * 64 * S;  // [hd][s]

  bf16x8 aq[2];
  int qrow = q0 + wave * 16 + la;
#pragma unroll
  for (int kc = 0; kc < 2; ++kc)
    aq[kc] = *(const bf16x8*)&Qb[(size_t)qrow * D + kc * 32 + quad * 8];

  f32x4 zero = {0.f, 0.f, 0.f, 0.f};
  f32x4 o[4];
  float m_r[4], l_r[4];
#pragma unroll
  for (int r = 0; r < 4; ++r) { m_r[r] = MASK; l_r[r] = 0.f; }
#pragma unroll
  for (int nt = 0; nt < 4; ++nt) o[nt] = zero;

  int ntiles = qt + 1;
  for (int t = 0; t < ntiles; ++t) {
    int kb = t * 64;
#pragma unroll
    for (int p = 0; p < 2; ++p) {
      int li = (tid + p * 256) * 8;
      int r = li >> 6, c = li & 63;
      *(bf16x8*)&Ks[r * LDK + c] = *(const bf16x8*)&Kb[(size_t)(kb + r) * D + c];
      *(bf16x8*)&Vs[r * LDK + c] = *(const bf16x8*)&Vb[(size_t)r * S + kb + c];
    }
    __syncthreads();

    f32x4 s[4];
#pragma unroll
    for (int nt = 0; nt < 4; ++nt) {
      bf16x8 bk0 = *(const bf16x8*)&Ks[(nt * 16 + la) * LDK + quad * 8];
      bf16x8 bk1 = *(const bf16x8*)&Ks[(nt * 16 + la) * LDK + 32 + quad * 8];
      f32x4 z = zero;
      z = MFMA16(aq[0], bk0, z);
      z = MFMA16(aq[1], bk1, z);
      s[nt] = z;
    }

#pragma unroll
    for (int r = 0; r < 4; ++r) {
      int qa = q0 + wave * 16 + quad * 4 + r;
      float mx = MASK;
#pragma unroll
      for (int nt = 0; nt < 4; ++nt) {
        int ka = kb + nt * 16 + la;
        float sv = s[nt][r] * SCL2;
        sv = (ka > qa) ? MASK : sv;
        s[nt][r] = sv;
        mx = fmaxf(mx, sv);
      }
#pragma unroll
      for (int off = 1; off < 16; off <<= 1) mx = fmaxf(mx, __shfl_xor(mx, off, 64));
      float mnew = fmaxf(m_r[r], mx);
      float alpha = exp2f(m_r[r] - mnew);
      float rs = 0.f;
#pragma unroll
      for (int nt = 0; nt < 4; ++nt) {
        float p = exp2f(s[nt][r] - mnew);
        s[nt][r] = p;
        rs += p;
      }
#pragma unroll
      for (int off = 1; off < 16; off <<= 1) rs += __shfl_xor(rs, off, 64);
      l_r[r] = l_r[r] * alpha + rs;
      m_r[r] = mnew;
#pragma unroll
      for (int nt = 0; nt < 4; ++nt) o[nt][r] *= alpha;
#pragma unroll
      for (int nt = 0; nt < 4; ++nt)
        Ps[wave][(quad * 4 + r) * LDK + nt * 16 + la] = (bf16)s[nt][r];
    }
    __syncthreads();

#pragma unroll
    for (int kc = 0; kc < 2; ++kc) {
      bf16x8 ap = *(const bf16x8*)&Ps[wave][la * LDK + kc * 32 + quad * 8];
#pragma unroll
      for (int nt = 0; nt < 4; ++nt) {
        bf16x8 bv = *(const bf16x8*)&Vs[(nt * 16 + la) * LDK + kc * 32 + quad * 8];
        o[nt] = MFMA16(ap, bv, o[nt]);
      }
    }
    __syncthreads();
  }

#pragma unroll
  for (int nt = 0; nt < 4; ++nt) {
    int hd = nt * 16 + la;
#pragma unroll
    for (int r = 0; r < 4; ++r) {
      int row = q0 + wave * 16 + quad * 4 + r;
      float inv = (l_r[r] > 1e-30f) ? 1.0f / l_r[r] : 0.0f;
      O[base + (size_t)row * D + hd] = (bf16)(o[nt][r] * inv);
    }
  }
}

extern "C" void kernel_launch(void* const* d_in, const int* in_sizes, int n_in,
                              void* d_out, int out_size, void* d_ws, size_t ws_size,
                              hipStream_t stream) {
  constexpr int B = 2, S = 2048, D = 1024;
  constexpr int M = B * S;
  constexpr size_t WN = (size_t)D * D;
  constexpr size_t XN = (size_t)M * D;

  const float* x = (const float*)d_in[0];
  const float* Wq = (const float*)d_in[1];
  const float* Wk = (const float*)d_in[2];
  const float* Wv = (const float*)d_in[3];
  const float* Wo = (const float*)d_in[4];
  float* out = (float*)d_out;

  if (ws_size < 2 * XN * sizeof(bf16)) return;
  bf16* Qb = (bf16*)d_ws;          // [0,8MB): Q, then O (flash aliases)
  bf16* Vtg = Qb + XN;             // [8,16MB): V^T [bh][hd][s]
  bf16* Wt = Vtg + XN;             // [16,24MB): 4x W^T bf16 (only if ws allows)
  bf16* Kb = (bf16*)d_out;         // d_out[0,8MB): K (scratch until final gemm)
  bf16* Vb = Kb + XN;              // d_out[8,16MB): V (dead after vtrans)
  bool use_bt = ws_size >= (2 * XN + 4 * WN) * sizeof(bf16);

  dim3 gq(M / 128, 24), gf(M / 128, 8);
  if (use_bt) {
    prep_wt<<<dim3(32, 32, 4), 256, 0, stream>>>(Wq, Wk, Wv, Wo, Wt, D);
    gemm3<float, bf16, true><<<gq, 256, 0, stream>>>(x, Wt, Wt + WN, Wt + 2 * WN,
                                                     Qb, Kb, Vb, M, D, D, 8);
  } else {
    gemm3<float, bf16, false><<<gq, 256, 0, stream>>>(x, Wq, Wk, Wv, Qb, Kb, Vb, M, D, D, 8);
  }
  vtrans<<<dim3(S / 32, 2, 32), 256, 0, stream>>>(Vb, Vtg);
  flash_attn<<<dim3(S / 64, 32), 256, 0, stream>>>(Qb, Kb, Vtg, Qb);
  if (use_bt) {
    gemm3<bf16, float, true><<<gf, 256, 0, stream>>>(Qb, Wt + 3 * WN, Wt + 3 * WN, Wt + 3 * WN,
                                                     out, out, out, M, D, D, 8);
  } else {
    gemm3<bf16, float, false><<<gf, 256, 0, stream>>>(Qb, Wo, Wo, Wo, out, out, out, M, D, D, 8);
  }
}

// Round 6
// 194.259 us; speedup vs baseline: 2.5166x; 1.4260x over previous
//
#include <hip/hip_runtime.h>
#include <hip/hip_bf16.h>
#include <cstdint>

typedef __bf16 bf16;
typedef bf16 bf16x8 __attribute__((ext_vector_type(8)));
typedef float f32x4 __attribute__((ext_vector_type(4)));

#define MFMA16(a, b, c) __builtin_amdgcn_mfma_f32_16x16x32_bf16(a, b, c, 0, 0, 0)

struct rawF { f32x4 a, b; };
__device__ inline rawF ldr(const float* p) {
  rawF r; r.a = *(const f32x4*)p; r.b = *(const f32x4*)(p + 4); return r;
}
__device__ inline bf16x8 ldr(const bf16* p) { return *(const bf16x8*)p; }
__device__ inline bf16x8 cv(const rawF& r) {
  bf16x8 o;
#pragma unroll
  for (int i = 0; i < 4; ++i) { o[i] = (bf16)r.a[i]; o[i + 4] = (bf16)r.b[i]; }
  return o;
}
__device__ inline bf16x8 cv(const bf16x8& r) { return r; }
__device__ inline void stC(bf16* C, size_t i, float v) { C[i] = (bf16)v; }
__device__ inline void stC(float* C, size_t i, float v) { C[i] = v; }

// ---- prep: transpose-convert 4 weights fp32 [K][N] -> bf16 [N][K] ----
__global__ __launch_bounds__(256) void prep_wt(const float* __restrict__ W0,
                                               const float* __restrict__ W1,
                                               const float* __restrict__ W2,
                                               const float* __restrict__ W3,
                                               bf16* __restrict__ Wt, int n) {
  const float* Ws[4] = {W0, W1, W2, W3};
  const float* W = Ws[blockIdx.z];
  bf16* out = Wt + (size_t)blockIdx.z * n * n;
  __shared__ bf16 t[32][33];
  int bx = blockIdx.x * 32, by = blockIdx.y * 32;
  int tx = threadIdx.x & 31, ty = threadIdx.x >> 5;
#pragma unroll
  for (int i = 0; i < 32; i += 8)
    t[ty + i][tx] = (bf16)W[(size_t)(by + ty + i) * n + bx + tx];
  __syncthreads();
#pragma unroll
  for (int i = 0; i < 32; i += 8)
    out[(size_t)(bx + ty + i) * n + by + tx] = t[tx][ty + i];
}

// ---- transpose V bf16 [b*s][D] -> Vt [bh][hd][2048] ----
__global__ __launch_bounds__(256) void vtrans(const bf16* __restrict__ V, bf16* __restrict__ Vt) {
  constexpr int Sn = 2048, Dn = 1024;
  __shared__ bf16 t[32][33];
  int s0 = blockIdx.x * 32, hd0 = blockIdx.y * 32, bh = blockIdx.z;
  int b = bh >> 4, h = bh & 15;
  int tx = threadIdx.x & 31, ty = threadIdx.x >> 5;
#pragma unroll
  for (int i = 0; i < 32; i += 8)
    t[ty + i][tx] = V[(size_t)(b * Sn + s0 + ty + i) * Dn + h * 64 + hd0 + tx];
  __syncthreads();
#pragma unroll
  for (int i = 0; i < 32; i += 8)
    Vt[(size_t)bh * 64 * Sn + (size_t)(hd0 + ty + i) * Sn + s0 + tx] = t[tx][ty + i];
}

// ---- GEMM C[M,N] = A[M,K] @ B; register-prefetched k-loop; 3 outputs via blockIdx.y ----
template <typename TA, typename TC, bool BT>
__global__ __launch_bounds__(256) void gemm3(const TA* __restrict__ A,
                                             const void* __restrict__ B0p,
                                             const void* __restrict__ B1p,
                                             const void* __restrict__ B2p,
                                             TC* __restrict__ C0, TC* __restrict__ C1,
                                             TC* __restrict__ C2, int M, int N, int K, int nblk) {
  constexpr int LDA = 40;
  constexpr int LDB = BT ? 40 : 32;
  __shared__ bf16 As[128 * LDA];
  __shared__ bf16 Bs[128 * LDB];
  int tid = threadIdx.x, wave = tid >> 6, lane = tid & 63;
  int la = lane & 15, quad = lane >> 4;
  int wr = (wave >> 1) * 64, wc = (wave & 1) * 64;
  int by = blockIdx.y;
  int sel = by / nblk;
  int n0 = (by - sel * nblk) * 128;
  const void* Bp = sel == 0 ? B0p : (sel == 1 ? B1p : B2p);
  TC* C = sel == 0 ? C0 : (sel == 1 ? C1 : C2);
  const TA* Ab = A + (size_t)blockIdx.x * 128 * K;
  using TB = typename std::conditional<BT, bf16, float>::type;
  const TB* Bm = (const TB*)Bp;

  // per-p staging indices
  int ar[2], ac[2], br[2], bc[2];
#pragma unroll
  for (int p = 0; p < 2; ++p) {
    int li = (tid + p * 256) * 8;
    ar[p] = li >> 5; ac[p] = li & 31;       // A: row, kcol
    if (BT) { br[p] = li >> 5; bc[p] = li & 31; }    // B^T: nrow, kcol
    else    { br[p] = li >> 7; bc[p] = li & 127; }   // B: krow, ncol
  }

  f32x4 zero = {0.f, 0.f, 0.f, 0.f};
  f32x4 acc[4][4];
#pragma unroll
  for (int i = 0; i < 4; ++i)
#pragma unroll
    for (int j = 0; j < 4; ++j) acc[i][j] = zero;

  decltype(ldr((const TA*)nullptr)) pa[2];
  decltype(ldr((const TB*)nullptr)) pb[2];
#pragma unroll
  for (int p = 0; p < 2; ++p) {
    pa[p] = ldr(&Ab[(size_t)ar[p] * K + ac[p]]);
    if (BT) pb[p] = ldr(&Bm[(size_t)(n0 + br[p]) * K + bc[p]]);
    else    pb[p] = ldr(&Bm[(size_t)br[p] * N + n0 + bc[p]]);
  }

  for (int k0 = 0; k0 < K; k0 += 32) {
#pragma unroll
    for (int p = 0; p < 2; ++p) {
      *(bf16x8*)&As[ar[p] * LDA + ac[p]] = cv(pa[p]);
      if constexpr (BT) {
        *(bf16x8*)&Bs[br[p] * LDB + bc[p]] = cv(pb[p]);
      } else {
        bf16x8 v = cv(pb[p]);
        int kx = br[p] ^ (((bc[p] >> 3) & 3) << 3);
#pragma unroll
        for (int j = 0; j < 8; ++j) Bs[(bc[p] + j) * 32 + kx] = v[j];
      }
    }
    __syncthreads();
    int k1 = k0 + 32;
    if (k1 < K) {
#pragma unroll
      for (int p = 0; p < 2; ++p) {
        pa[p] = ldr(&Ab[(size_t)ar[p] * K + k1 + ac[p]]);
        if (BT) pb[p] = ldr(&Bm[(size_t)(n0 + br[p]) * K + k1 + bc[p]]);
        else    pb[p] = ldr(&Bm[(size_t)(k1 + br[p]) * N + n0 + bc[p]]);
      }
    }
    bf16x8 af[4], bfr[4];
#pragma unroll
    for (int i = 0; i < 4; ++i)
      af[i] = *(const bf16x8*)&As[(wr + i * 16 + la) * LDA + quad * 8];
#pragma unroll
    for (int j = 0; j < 4; ++j) {
      int nr = wc + j * 16 + la;
      if constexpr (BT)
        bfr[j] = *(const bf16x8*)&Bs[nr * LDB + quad * 8];
      else
        bfr[j] = *(const bf16x8*)&Bs[nr * 32 + ((quad * 8) ^ (((nr >> 3) & 3) << 3))];
    }
#pragma unroll
    for (int i = 0; i < 4; ++i)
#pragma unroll
      for (int j = 0; j < 4; ++j) acc[i][j] = MFMA16(af[i], bfr[j], acc[i][j]);
    __syncthreads();
  }
#pragma unroll
  for (int i = 0; i < 4; ++i) {
#pragma unroll
    for (int j = 0; j < 4; ++j) {
      int col = n0 + wc + j * 16 + la;
#pragma unroll
      for (int r = 0; r < 4; ++r) {
        int row = blockIdx.x * 128 + wr + i * 16 + quad * 4 + r;
        stC(C, (size_t)row * N + col, acc[i][j][r]);
      }
    }
  }
}

// ---- flash attention, causal, HD=64; transposed scores (S^T = K@Q^T) ----
// grid (16, 32): block handles q-tiles (31-bx) and (bx) => uniform 33 tiles/block.
// Each lane owns ONE q-row's softmax state (q = la); in-lane reductions + 2 shfl.
// Register prefetch of next K/V tile hides global latency; 2 barriers/tile.
__global__ __launch_bounds__(256) void flash_attn(const bf16* __restrict__ Q,
                                                  const bf16* __restrict__ Kg,
                                                  const bf16* __restrict__ Vtg,
                                                  bf16* __restrict__ O) {
  constexpr int D = 1024, S = 2048;
  const int LDK = 72, LDP = 72;
  const float MASK = -3.0e4f;
  const float SCL2 = 0.18033688011112042f;  // log2(e)/sqrt(64)
  __shared__ bf16 Ks[64 * 72];     // [key][hd]
  __shared__ bf16 Vs[64 * 72];     // [hd][key]
  __shared__ bf16 Ps[4][16 * 72];  // per-wave P [q][key]

  int bx = blockIdx.x, bh = blockIdx.y;
  int b = bh >> 4, h = bh & 15;
  int tid = threadIdx.x, wave = tid >> 6, lane = tid & 63;
  int la = lane & 15, quad = lane >> 4;
  const size_t base = (size_t)b * S * D + (size_t)h * 64;
  const bf16* Qg = Q + base;
  const bf16* Kb = Kg + base;
  const bf16* Vb = Vtg + (size_t)bh * 64 * S;  // [hd][s]
  int r0 = tid >> 3, c0 = (tid & 7) * 8;       // staging: rows r0,r0+32; col chunk c0

  f32x4 zero = {0.f, 0.f, 0.f, 0.f};

#pragma unroll
  for (int seg = 0; seg < 2; ++seg) {
    int qt = seg == 0 ? 31 - bx : bx;
    int q0 = qt * 64;
    int ntiles = qt + 1;

    // Q B-frags (pre-scaled by SCL2): lane la holds Q[q0+wave*16+la][quad*8+j]
    bf16x8 aq[2];
    {
      int qrow = q0 + wave * 16 + la;
#pragma unroll
      for (int kc = 0; kc < 2; ++kc) {
        bf16x8 t = *(const bf16x8*)&Qg[(size_t)qrow * D + kc * 32 + quad * 8];
#pragma unroll
        for (int i = 0; i < 8; ++i) t[i] = (bf16)((float)t[i] * SCL2);
        aq[kc] = t;
      }
    }

    f32x4 o[4];
#pragma unroll
    for (int nt = 0; nt < 4; ++nt) o[nt] = zero;
    float m_l = MASK, l_l = 0.f;

    // prefetch tile 0
    bf16x8 kr0 = *(const bf16x8*)&Kb[(size_t)r0 * D + c0];
    bf16x8 kr1 = *(const bf16x8*)&Kb[(size_t)(r0 + 32) * D + c0];
    bf16x8 vr0 = *(const bf16x8*)&Vb[(size_t)r0 * S + c0];
    bf16x8 vr1 = *(const bf16x8*)&Vb[(size_t)(r0 + 32) * S + c0];

    for (int t = 0; t < ntiles; ++t) {
      int kb = t * 64;
      *(bf16x8*)&Ks[r0 * LDK + c0] = kr0;
      *(bf16x8*)&Ks[(r0 + 32) * LDK + c0] = kr1;
      *(bf16x8*)&Vs[r0 * LDK + c0] = vr0;
      *(bf16x8*)&Vs[(r0 + 32) * LDK + c0] = vr1;
      __syncthreads();
      if (t + 1 < ntiles) {  // prefetch next tile (latency hidden behind compute)
        int kb2 = kb + 64;
        kr0 = *(const bf16x8*)&Kb[(size_t)(kb2 + r0) * D + c0];
        kr1 = *(const bf16x8*)&Kb[(size_t)(kb2 + r0 + 32) * D + c0];
        vr0 = *(const bf16x8*)&Vb[(size_t)r0 * S + kb2 + c0];
        vr1 = *(const bf16x8*)&Vb[(size_t)(r0 + 32) * S + kb2 + c0];
      }

      // S^T = K @ Q^T : lane holds S[q=la][key = kb + nt*16 + quad*4 + r]
      f32x4 s[4];
#pragma unroll
      for (int nt = 0; nt < 4; ++nt) {
        bf16x8 k0f = *(const bf16x8*)&Ks[(nt * 16 + la) * LDK + quad * 8];
        bf16x8 k1f = *(const bf16x8*)&Ks[(nt * 16 + la) * LDK + 32 + quad * 8];
        f32x4 z = zero;
        z = MFMA16(k0f, aq[0], z);
        z = MFMA16(k1f, aq[1], z);
        s[nt] = z;
      }

      // mask only the diagonal tile
      if (t == qt) {
        int qa = q0 + wave * 16 + la;
#pragma unroll
        for (int nt = 0; nt < 4; ++nt)
#pragma unroll
          for (int r = 0; r < 4; ++r) {
            int ka = kb + nt * 16 + quad * 4 + r;
            s[nt][r] = (ka > qa) ? MASK : s[nt][r];
          }
      }

      // online softmax: in-lane over 16 keys, then cross-quad butterfly
      float mx = m_l;
#pragma unroll
      for (int nt = 0; nt < 4; ++nt)
#pragma unroll
        for (int r = 0; r < 4; ++r) mx = fmaxf(mx, s[nt][r]);
      mx = fmaxf(mx, __shfl_xor(mx, 16, 64));
      mx = fmaxf(mx, __shfl_xor(mx, 32, 64));
      float alpha = exp2f(m_l - mx);
      float rs = 0.f;
#pragma unroll
      for (int nt = 0; nt < 4; ++nt)
#pragma unroll
        for (int r = 0; r < 4; ++r) {
          float p = exp2f(s[nt][r] - mx);
          s[nt][r] = p;
          rs += p;
        }
      rs += __shfl_xor(rs, 16, 64);
      rs += __shfl_xor(rs, 32, 64);
      l_l = l_l * alpha + rs;
      m_l = mx;

      // spill P (wave-private; in-wave LDS order + waitcnt make this safe)
#pragma unroll
      for (int nt = 0; nt < 4; ++nt)
#pragma unroll
        for (int r = 0; r < 4; ++r)
          Ps[wave][la * LDP + nt * 16 + quad * 4 + r] = (bf16)s[nt][r];

      // rescale O rows: alpha lives at lane la==row; broadcast
      float ab[4];
#pragma unroll
      for (int r = 0; r < 4; ++r) ab[r] = __shfl(alpha, quad * 4 + r, 64);
#pragma unroll
      for (int nt = 0; nt < 4; ++nt)
#pragma unroll
        for (int r = 0; r < 4; ++r) o[nt][r] *= ab[r];

      // O += P @ V
#pragma unroll
      for (int kc = 0; kc < 2; ++kc) {
        bf16x8 ap = *(const bf16x8*)&Ps[wave][la * LDP + kc * 32 + quad * 8];
#pragma unroll
        for (int nt = 0; nt < 4; ++nt) {
          bf16x8 bv = *(const bf16x8*)&Vs[(nt * 16 + la) * LDK + kc * 32 + quad * 8];
          o[nt] = MFMA16(ap, bv, o[nt]);
        }
      }
      __syncthreads();  // protect Ks/Vs for next tile / next segment
    }

    // epilogue: l lives at lane la==row; broadcast, normalize, store
    float inv[4];
#pragma unroll
    for (int r = 0; r < 4; ++r) {
      float lv = __shfl(l_l, quad * 4 + r, 64);
      inv[r] = (lv > 1e-30f) ? 1.0f / lv : 0.0f;
    }
#pragma unroll
    for (int nt = 0; nt < 4; ++nt) {
      int hd = nt * 16 + la;
#pragma unroll
      for (int r = 0; r < 4; ++r) {
        int row = q0 + wave * 16 + quad * 4 + r;
        O[base + (size_t)row * D + hd] = (bf16)(o[nt][r] * inv[r]);
      }
    }
  }
}

extern "C" void kernel_launch(void* const* d_in, const int* in_sizes, int n_in,
                              void* d_out, int out_size, void* d_ws, size_t ws_size,
                              hipStream_t stream) {
  constexpr int B = 2, S = 2048, D = 1024;
  constexpr int M = B * S;
  constexpr size_t WN = (size_t)D * D;
  constexpr size_t XN = (size_t)M * D;

  const float* x = (const float*)d_in[0];
  const float* Wq = (const float*)d_in[1];
  const float* Wk = (const float*)d_in[2];
  const float* Wv = (const float*)d_in[3];
  const float* Wo = (const float*)d_in[4];
  float* out = (float*)d_out;

  if (ws_size < 2 * XN * sizeof(bf16)) return;
  bf16* Qb = (bf16*)d_ws;   // [0,8MB): Q, then O (flash aliases)
  bf16* Vtg = Qb + XN;      // [8,16MB): V^T [bh][hd][s]
  bf16* Wt = Vtg + XN;      // [16,24MB): 4x W^T bf16 (if ws allows)
  bf16* Kb = (bf16*)d_out;  // d_out[0,8MB): K (scratch until final gemm)
  bf16* Vb = Kb + XN;       // d_out[8,16MB): V (dead after vtrans)
  bool use_bt = ws_size >= (2 * XN + 4 * WN) * sizeof(bf16);

  dim3 gq(M / 128, 24), gf(M / 128, 8);
  if (use_bt) {
    prep_wt<<<dim3(32, 32, 4), 256, 0, stream>>>(Wq, Wk, Wv, Wo, Wt, D);
    gemm3<float, bf16, true><<<gq, 256, 0, stream>>>(x, Wt, Wt + WN, Wt + 2 * WN,
                                                     Qb, Kb, Vb, M, D, D, 8);
  } else {
    gemm3<float, bf16, false><<<gq, 256, 0, stream>>>(x, Wq, Wk, Wv, Qb, Kb, Vb, M, D, D, 8);
  }
  vtrans<<<dim3(S / 32, 2, 32), 256, 0, stream>>>(Vb, Vtg);
  flash_attn<<<dim3(16, 32), 256, 0, stream>>>(Qb, Kb, Vtg, Qb);
  if (use_bt) {
    gemm3<bf16, float, true><<<gf, 256, 0, stream>>>(Qb, Wt + 3 * WN, Wt + 3 * WN, Wt + 3 * WN,
                                                     out, out, out, M, D, D, 8);
  } else {
    gemm3<bf16, float, false><<<gf, 256, 0, stream>>>(Qb, Wo, Wo, Wo, out, out, out, M, D, D, 8);
  }
}